// Round 1
// baseline (14838.544 us; speedup 1.0000x reference)
//
#include <hip/hip_runtime.h>

#define P 256     // H*W
#define CDIM 256
#define SDIM 32
#define BDIM 16

// Kernel A: ehb1[b,a,p] = sum_c W1[a,c]*hid[b,c,p] + b1[a]
__global__ __launch_bounds__(256) void eh_kernel(const float* __restrict__ hid,
                                                 const float* __restrict__ W1,
                                                 const float* __restrict__ b1,
                                                 float* __restrict__ ehb1) {
    const int bi = blockIdx.x;        // [0,256)
    const int b  = bi >> 4;
    const int ab = (bi & 15) << 4;    // 16 a-rows per block
    const int p  = threadIdx.x;
    float acc[16];
#pragma unroll
    for (int i = 0; i < 16; ++i) acc[i] = 0.f;
    const float* hb = hid + (size_t)b * CDIM * P;
    for (int c = 0; c < CDIM; c += 8) {
        float hv[8];
#pragma unroll
        for (int j = 0; j < 8; ++j) hv[j] = hb[(c + j) * P + p];
#pragma unroll
        for (int i = 0; i < 16; ++i) {
            const float* wr = W1 + (size_t)(ab + i) * 512 + c;  // W1h row, contiguous -> s_load_dwordx8
#pragma unroll
            for (int j = 0; j < 8; ++j) acc[i] = fmaf(wr[j], hv[j], acc[i]);
        }
    }
#pragma unroll
    for (int i = 0; i < 16; ++i)
        ehb1[((size_t)b * CDIM + ab + i) * P + p] = acc[i] + b1[ab + i];
}

// Kernel B: energy[b,s] = mean_p sum_a W2[a]*tanh(ee[b,s,a,p] + ehb1[b,a,p]) + b2
__global__ __launch_bounds__(1024, 4) void energy_kernel(const float* __restrict__ enc,
                                                         const float* __restrict__ W1,
                                                         const float* __restrict__ W2,
                                                         const float* __restrict__ b2,
                                                         const float* __restrict__ ehb1,
                                                         float* __restrict__ energy) {
    __shared__ float lds[32 * P];   // 32 KB c-tile of encoder
    __shared__ float red[16];
    const int bs  = blockIdx.x;     // b*32+s
    const int b   = bs >> 5;
    const int tid = threadIdx.x;
    const int g   = tid >> 8;       // a-group 0..3 (wave-uniform: W1 index -> s_load)
    const int p   = tid & 255;      // pixel
    float acc[64];
#pragma unroll
    for (int i = 0; i < 64; ++i) acc[i] = 0.f;
    const float* eb = enc + (size_t)bs * CDIM * P;
    for (int ct = 0; ct < 8; ++ct) {
        const int c0 = ct * 32;
        __syncthreads();
        // c-tile x all-p is contiguous in global: straight 32KB copy
#pragma unroll
        for (int k = 0; k < 8; ++k) {
            const int idx = tid + k * 1024;
            lds[idx] = eb[c0 * P + idx];
        }
        __syncthreads();
#pragma unroll
        for (int cs = 0; cs < 4; ++cs) {
            float ev[8];
#pragma unroll
            for (int j = 0; j < 8; ++j) ev[j] = lds[(cs * 8 + j) * P + p];
            const float* wbase = W1 + 256 + c0 + cs * 8;   // W1e = W1[:,256:]
#pragma unroll
            for (int i = 0; i < 64; ++i) {
                const float* wr = wbase + (size_t)(g * 64 + i) * 512; // contiguous 8 -> s_load_dwordx8
#pragma unroll
                for (int j = 0; j < 8; ++j) acc[i] = fmaf(wr[j], ev[j], acc[i]);
            }
        }
    }
    // epilogue: tanh + W2 dot
    float ep = 0.f;
    const float* ehb = ehb1 + ((size_t)b * CDIM + g * 64) * P + p;
#pragma unroll
    for (int i = 0; i < 64; ++i) {
        const float x  = acc[i] + ehb[(size_t)i * P];
        const float ex = __expf(2.f * x);
        const float t  = 1.f - 2.f / (ex + 1.f);   // exact tanh identity
        ep = fmaf(W2[g * 64 + i], t, ep);
    }
#pragma unroll
    for (int off = 32; off > 0; off >>= 1) ep += __shfl_down(ep, off, 64);
    if ((tid & 63) == 0) red[tid >> 6] = ep;
    __syncthreads();
    if (tid == 0) {
        float s = 0.f;
#pragma unroll
        for (int w = 0; w < 16; ++w) s += red[w];
        energy[bs] = s * (1.f / 256.f) + b2[0];
    }
}

// Kernel C: softmax over S=32 for each of 16 batches (one block)
__global__ __launch_bounds__(512) void softmax_kernel(const float* __restrict__ energy,
                                                      float* __restrict__ wts) {
    const int tid = threadIdx.x;   // 512 = 16 rows x 32
    const int r = tid >> 5;
    const int s = tid & 31;
    float e = energy[r * 32 + s];
    float m = e;
#pragma unroll
    for (int off = 16; off > 0; off >>= 1) m = fmaxf(m, __shfl_xor(m, off, 64));
    const float ex = __expf(e - m);
    float sum = ex;
#pragma unroll
    for (int off = 16; off > 0; off >>= 1) sum += __shfl_xor(sum, off, 64);
    wts[r * 32 + s] = ex / sum;
}

// Kernel D: context[b,c,p] = sum_s w[b,s]*enc[b,s,c,p]  (float4 coalesced)
__global__ __launch_bounds__(256) void context_kernel(const float4* __restrict__ enc4,
                                                      const float* __restrict__ wts,
                                                      float4* __restrict__ out4) {
    const int bi = blockIdx.x;                       // 1024
    const int b  = bi >> 6;
    const int i4 = ((bi & 63) << 8) + threadIdx.x;   // [0,16384) float4s over C*P
    float4 acc = {0.f, 0.f, 0.f, 0.f};
    const float4* eb = enc4 + (size_t)b * SDIM * 16384 + i4;
#pragma unroll 4
    for (int s = 0; s < SDIM; ++s) {
        const float wv = wts[b * SDIM + s];          // uniform -> scalar load
        const float4 v = eb[(size_t)s * 16384];
        acc.x = fmaf(wv, v.x, acc.x);
        acc.y = fmaf(wv, v.y, acc.y);
        acc.z = fmaf(wv, v.z, acc.z);
        acc.w = fmaf(wv, v.w, acc.w);
    }
    out4[(size_t)b * 16384 + i4] = acc;
}

extern "C" void kernel_launch(void* const* d_in, const int* in_sizes, int n_in,
                              void* d_out, int out_size, void* d_ws, size_t ws_size,
                              hipStream_t stream) {
    const float* hid = (const float*)d_in[0];
    const float* enc = (const float*)d_in[1];
    const float* W1  = (const float*)d_in[2];
    const float* b1  = (const float*)d_in[3];
    const float* W2  = (const float*)d_in[4];
    const float* b2  = (const float*)d_in[5];
    float* out = (float*)d_out;

    float* ehb1   = out;                // reuse d_out (exactly B*A*P floats) as scratch;
                                        // fully overwritten by context_kernel at the end
    float* energy = (float*)d_ws;       // 512 floats
    float* wts    = energy + 512;       // 512 floats

    eh_kernel<<<256, 256, 0, stream>>>(hid, W1, b1, ehb1);
    energy_kernel<<<512, 1024, 0, stream>>>(enc, W1, W2, b2, ehb1, energy);
    softmax_kernel<<<1, 512, 0, stream>>>(energy, wts);
    context_kernel<<<1024, 256, 0, stream>>>((const float4*)enc, wts, (float4*)out);
}

// Round 2
// 2834.003 us; speedup vs baseline: 5.2359x; 5.2359x over previous
//
#include <hip/hip_runtime.h>

#define P 256     // H*W
#define CDIM 256
#define SDIM 32
#define BDIM 16

// Kernel A: ehb1[b,a,p] = sum_c W1[a,c]*hid[b,c,p] + b1[a]
__global__ __launch_bounds__(256) void eh_kernel(const float* __restrict__ hid,
                                                 const float* __restrict__ W1,
                                                 const float* __restrict__ b1,
                                                 float* __restrict__ ehb1) {
    const int bi = blockIdx.x;        // [0,256)
    const int b  = bi >> 4;
    const int ab = (bi & 15) << 4;    // 16 a-rows per block
    const int p  = threadIdx.x;
    float acc[16];
#pragma unroll
    for (int i = 0; i < 16; ++i) acc[i] = 0.f;
    const float* hb = hid + (size_t)b * CDIM * P;
    for (int c = 0; c < CDIM; c += 8) {
        float hv[8];
#pragma unroll
        for (int j = 0; j < 8; ++j) hv[j] = hb[(c + j) * P + p];
#pragma unroll
        for (int i = 0; i < 16; ++i) {
            const float* wr = W1 + (size_t)(ab + i) * 512 + c;  // W1h row -> s_load
#pragma unroll
            for (int j = 0; j < 8; ++j) acc[i] = fmaf(wr[j], hv[j], acc[i]);
        }
    }
#pragma unroll
    for (int i = 0; i < 16; ++i)
        ehb1[((size_t)b * CDIM + ab + i) * P + p] = acc[i] + b1[ab + i];
}

// Kernel B: energy[b,s] = mean_p sum_a W2[a]*tanh(ee[b,s,a,p] + ehb1[b,a,p]) + b2
// Block per (b,s). Four a-quarter passes with acc[16]/thread (NO spill),
// per-quarter epilogue folds tanh+W2 into a running scalar.
__global__ __launch_bounds__(1024) void energy_kernel(const float* __restrict__ enc,
                                                      const float* __restrict__ W1,
                                                      const float* __restrict__ W2,
                                                      const float* __restrict__ b2,
                                                      const float* __restrict__ ehb1,
                                                      float* __restrict__ energy) {
    __shared__ float lds[32 * P];   // 32 KB c-tile of encoder
    __shared__ float red[16];
    const int bs  = blockIdx.x;     // b*32+s
    const int b   = bs >> 5;
    const int tid = threadIdx.x;
    const int g   = tid >> 8;       // a-subgroup 0..3 (wave-uniform)
    const int p   = tid & 255;      // pixel
    float ep = 0.f;
    const float* eb = enc + (size_t)bs * CDIM * P;

    for (int q = 0; q < 4; ++q) {
        const int abase = q * 64 + g * 16;
        float acc[16];
#pragma unroll
        for (int i = 0; i < 16; ++i) acc[i] = 0.f;

        for (int ct = 0; ct < 8; ++ct) {
            const int c0 = ct * 32;
            __syncthreads();
            // stage 32c x 256p tile: contiguous 32KB, float4 (re-reads hit L2/L3)
            {
                const float4* eb4 = (const float4*)(eb + c0 * P);
                float4* lds4 = (float4*)lds;
                lds4[tid]        = eb4[tid];
                lds4[tid + 1024] = eb4[tid + 1024];
            }
            __syncthreads();
#pragma unroll
            for (int cs = 0; cs < 4; ++cs) {
                float ev[8];
#pragma unroll
                for (int j = 0; j < 8; ++j) ev[j] = lds[(cs * 8 + j) * P + p];
                const float* wbase = W1 + 256 + c0 + cs * 8;   // W1e = W1[:,256:]
#pragma unroll
                for (int i = 0; i < 16; ++i) {
                    const float* wr = wbase + (size_t)(abase + i) * 512;  // s_load (uniform)
#pragma unroll
                    for (int j = 0; j < 8; ++j) acc[i] = fmaf(wr[j], ev[j], acc[i]);
                }
            }
        }
        // epilogue for this a-quarter: tanh + W2 dot
        const float* ehb = ehb1 + ((size_t)b * CDIM + abase) * P + p;
#pragma unroll
        for (int i = 0; i < 16; ++i) {
            const float x  = acc[i] + ehb[(size_t)i * P];
            const float ex = __expf(2.f * x);
            const float t  = 1.f - 2.f / (ex + 1.f);   // exact tanh identity
            ep = fmaf(W2[abase + i], t, ep);
        }
    }

#pragma unroll
    for (int off = 32; off > 0; off >>= 1) ep += __shfl_down(ep, off, 64);
    if ((tid & 63) == 0) red[tid >> 6] = ep;
    __syncthreads();
    if (tid == 0) {
        float s = 0.f;
#pragma unroll
        for (int w = 0; w < 16; ++w) s += red[w];
        energy[bs] = s * (1.f / 256.f) + b2[0];
    }
}

// Kernel C: softmax over S=32 for each of 16 batches (one block)
__global__ __launch_bounds__(512) void softmax_kernel(const float* __restrict__ energy,
                                                      float* __restrict__ wts) {
    const int tid = threadIdx.x;   // 512 = 16 rows x 32
    const int r = tid >> 5;
    const int s = tid & 31;
    float e = energy[r * 32 + s];
    float m = e;
#pragma unroll
    for (int off = 16; off > 0; off >>= 1) m = fmaxf(m, __shfl_xor(m, off, 64));
    const float ex = __expf(e - m);
    float sum = ex;
#pragma unroll
    for (int off = 16; off > 0; off >>= 1) sum += __shfl_xor(sum, off, 64);
    wts[r * 32 + s] = ex / sum;
}

// Kernel D: context[b,c,p] = sum_s w[b,s]*enc[b,s,c,p]  (float4 coalesced)
__global__ __launch_bounds__(256) void context_kernel(const float4* __restrict__ enc4,
                                                      const float* __restrict__ wts,
                                                      float4* __restrict__ out4) {
    const int bi = blockIdx.x;                       // 1024
    const int b  = bi >> 6;
    const int i4 = ((bi & 63) << 8) + threadIdx.x;   // [0,16384) float4s over C*P
    float4 acc = {0.f, 0.f, 0.f, 0.f};
    const float4* eb = enc4 + (size_t)b * SDIM * 16384 + i4;
#pragma unroll 4
    for (int s = 0; s < SDIM; ++s) {
        const float wv = wts[b * SDIM + s];          // uniform -> scalar load
        const float4 v = eb[(size_t)s * 16384];
        acc.x = fmaf(wv, v.x, acc.x);
        acc.y = fmaf(wv, v.y, acc.y);
        acc.z = fmaf(wv, v.z, acc.z);
        acc.w = fmaf(wv, v.w, acc.w);
    }
    out4[(size_t)b * 16384 + i4] = acc;
}

extern "C" void kernel_launch(void* const* d_in, const int* in_sizes, int n_in,
                              void* d_out, int out_size, void* d_ws, size_t ws_size,
                              hipStream_t stream) {
    const float* hid = (const float*)d_in[0];
    const float* enc = (const float*)d_in[1];
    const float* W1  = (const float*)d_in[2];
    const float* b1  = (const float*)d_in[3];
    const float* W2  = (const float*)d_in[4];
    const float* b2  = (const float*)d_in[5];
    float* out = (float*)d_out;

    float* ehb1   = out;                // reuse d_out (exactly B*A*P floats) as scratch;
                                        // fully overwritten by context_kernel at the end
    float* energy = (float*)d_ws;       // 512 floats
    float* wts    = energy + 512;       // 512 floats

    eh_kernel<<<256, 256, 0, stream>>>(hid, W1, b1, ehb1);
    energy_kernel<<<512, 1024, 0, stream>>>(enc, W1, W2, b2, ehb1, energy);
    softmax_kernel<<<1, 512, 0, stream>>>(energy, wts);
    context_kernel<<<1024, 256, 0, stream>>>((const float4*)enc, wts, (float4*)out);
}

// Round 3
// 144.329 us; speedup vs baseline: 102.8103x; 19.6357x over previous
//
#include <hip/hip_runtime.h>

#define P 256     // H*W
#define CDIM 256
#define SDIM 32
#define BDIM 16

typedef __attribute__((ext_vector_type(8))) short short8;   // 8 bf16 = 4 VGPR
typedef __attribute__((ext_vector_type(4))) float f32x4;
typedef __attribute__((ext_vector_type(4))) unsigned int uint4v;
typedef __attribute__((ext_vector_type(2))) unsigned int uint2v;

__device__ inline unsigned int pack2bf(float lo, float hi) {
    unsigned int ul = __builtin_bit_cast(unsigned int, lo);
    unsigned int uh = __builtin_bit_cast(unsigned int, hi);
    ul += 0x7fffu + ((ul >> 16) & 1u);   // RNE
    uh += 0x7fffu + ((uh >> 16) & 1u);
    return (ul >> 16) | (uh & 0xffff0000u);
}

// Kernel A: ehb1[b,a,p] = sum_c W1h[a,c]*hid[b,c,p] + b1[a]   (fp32, exact)
__global__ __launch_bounds__(256) void eh_kernel(const float* __restrict__ hid,
                                                 const float* __restrict__ W1,
                                                 const float* __restrict__ b1,
                                                 float* __restrict__ ehb1) {
    const int bi = blockIdx.x;        // [0,256)
    const int b  = bi >> 4;
    const int ab = (bi & 15) << 4;    // 16 a-rows per block (block-uniform -> s_load W1)
    const int p  = threadIdx.x;
    float acc[16];
#pragma unroll
    for (int i = 0; i < 16; ++i) acc[i] = 0.f;
    const float* hb = hid + (size_t)b * CDIM * P;
    for (int c = 0; c < CDIM; c += 8) {
        float hv[8];
#pragma unroll
        for (int j = 0; j < 8; ++j) hv[j] = hb[(c + j) * P + p];
#pragma unroll
        for (int i = 0; i < 16; ++i) {
            const float* wr = W1 + (size_t)(ab + i) * 512 + c;
#pragma unroll
            for (int j = 0; j < 8; ++j) acc[i] = fmaf(wr[j], hv[j], acc[i]);
        }
    }
#pragma unroll
    for (int i = 0; i < 16; ++i)
        ehb1[((size_t)b * CDIM + ab + i) * P + p] = acc[i] + b1[ab + i];
}

// Kernel B: bf16-MFMA energy. Block = (b,s,p-half): T = W1e(256a x 256c) @ encT(256c x 128p),
// epilogue tanh(T+ehb1) dot W2, block-reduce -> partial[bid].
// LDS tiles swizzled: byte ^= ((row&7)<<4) on 128B rows (conflict-free ds_read_b128/writes).
__global__ __launch_bounds__(512, 4) void energy_mfma(const float* __restrict__ enc,
                                                      const float* __restrict__ W1,
                                                      const float* __restrict__ W2,
                                                      const float* __restrict__ ehb1,
                                                      float* __restrict__ partial) {
    __shared__ __align__(16) unsigned char ldsA[256 * 128];  // W1e tile [256a][64c] bf16, 32KB
    __shared__ __align__(16) unsigned char ldsB[128 * 128];  // encT tile [128p][64c] bf16, 16KB
    __shared__ float red[8];
    const int bid = blockIdx.x;          // 1024
    const int bs  = bid >> 1;            // b*32+s
    const int ph  = bid & 1;             // p-half
    const int b   = bs >> 5;
    const int tid = threadIdx.x;
    const int l   = tid & 63;
    const int w   = tid >> 6;            // wave 0..7
    const int a0w = (w >> 1) * 64;       // wave tile: 64a x 64p
    const int p0w = (w & 1) * 64;
    const int g   = l >> 4;              // lane quad-group
    const int i16 = l & 15;

    const float* eb = enc + (size_t)bs * (CDIM * P) + ph * 128;

    f32x4 acc[4][4];
#pragma unroll
    for (int m = 0; m < 4; ++m)
#pragma unroll
        for (int n = 0; n < 4; ++n) acc[m][n] = (f32x4){0.f, 0.f, 0.f, 0.f};

    for (int kt = 0; kt < 4; ++kt) {
        const int cbase = kt * 64;
        __syncthreads();
        // --- stage encT tile: thread covers 16 consecutive c at one p ---
        {
            const int p_l = tid & 127;
            const int cg  = tid >> 7;                      // 0..3
            const float* src = eb + (size_t)(cbase + cg * 16) * P + p_l;
            float v[16];
#pragma unroll
            for (int j = 0; j < 16; ++j) v[j] = src[(size_t)j * P];
            const int xr = (p_l & 7) << 4;
#pragma unroll
            for (int khw = 0; khw < 2; ++khw) {
                uint4v u;
                u.x = pack2bf(v[khw * 8 + 0], v[khw * 8 + 1]);
                u.y = pack2bf(v[khw * 8 + 2], v[khw * 8 + 3]);
                u.z = pack2bf(v[khw * 8 + 4], v[khw * 8 + 5]);
                u.w = pack2bf(v[khw * 8 + 6], v[khw * 8 + 7]);
                *(uint4v*)(ldsB + p_l * 128 + (((cg * 2 + khw) * 16) ^ xr)) = u;
            }
        }
        // --- stage W1e tile: wave reads 4 a-rows x 64c per iter (coalesced float4) ---
        {
#pragma unroll
            for (int it = 0; it < 8; ++it) {
                const int a_row = it * 32 + w * 4 + g;
                const float4 f = *(const float4*)(W1 + (size_t)a_row * 512 + 256 + cbase + i16 * 4);
                uint2v u;
                u.x = pack2bf(f.x, f.y);
                u.y = pack2bf(f.z, f.w);
                *(uint2v*)(ldsA + a_row * 128 + ((i16 * 8) ^ ((a_row & 7) << 4))) = u;
            }
        }
        __syncthreads();
        // --- MFMA: two K=32 halves of the 64c tile ---
#pragma unroll
        for (int kh = 0; kh < 2; ++kh) {
            const int slot = (kh * 4 + g) * 16;
            const int x7   = (l & 7) << 4;
            short8 af[4], bf[4];
#pragma unroll
            for (int m = 0; m < 4; ++m) {
                const int row = a0w + m * 16 + i16;
                af[m] = __builtin_bit_cast(short8, *(const uint4v*)(ldsA + row * 128 + (slot ^ x7)));
            }
#pragma unroll
            for (int n = 0; n < 4; ++n) {
                const int row = p0w + n * 16 + i16;
                bf[n] = __builtin_bit_cast(short8, *(const uint4v*)(ldsB + row * 128 + (slot ^ x7)));
            }
#pragma unroll
            for (int m = 0; m < 4; ++m)
#pragma unroll
                for (int n = 0; n < 4; ++n)
                    acc[m][n] = __builtin_amdgcn_mfma_f32_16x16x32_bf16(af[m], bf[n], acc[m][n], 0, 0, 0);
        }
    }

    // --- epilogue: x = acc + ehb1; tanh; dot W2; reduce ---
    float ep = 0.f;
    const float* ehbB = ehb1 + (size_t)b * (CDIM * P);
#pragma unroll
    for (int m = 0; m < 4; ++m) {
#pragma unroll
        for (int r = 0; r < 4; ++r) {
            const int a = a0w + m * 16 + g * 4 + r;      // C/D: row=(lane>>4)*4+reg
            const float w2v = W2[a];
            const float* ehr = ehbB + (size_t)a * P + ph * 128 + p0w + i16;
#pragma unroll
            for (int n = 0; n < 4; ++n) {
                const float x  = acc[m][n][r] + ehr[n * 16];
                const float ex = __expf(2.f * x);
                const float t  = 1.f - 2.f / (ex + 1.f);
                ep = fmaf(w2v, t, ep);
            }
        }
    }
#pragma unroll
    for (int off = 32; off > 0; off >>= 1) ep += __shfl_down(ep, off, 64);
    if (l == 0) red[w] = ep;
    __syncthreads();
    if (tid == 0) {
        float s = 0.f;
#pragma unroll
        for (int ww = 0; ww < 8; ++ww) s += red[ww];
        partial[bid] = s;
    }
}

// Kernel C: combine p-half partials + softmax over S=32 per batch
__global__ __launch_bounds__(512) void softmax_kernel(const float* __restrict__ partial,
                                                      const float* __restrict__ b2,
                                                      float* __restrict__ wts) {
    const int tid = threadIdx.x;   // 512 = 16 rows x 32
    const int r = tid >> 5;
    const int s = tid & 31;
    const int bs = r * 32 + s;
    float e = (partial[bs * 2] + partial[bs * 2 + 1]) * (1.f / 256.f) + b2[0];
    float m = e;
#pragma unroll
    for (int off = 16; off > 0; off >>= 1) m = fmaxf(m, __shfl_xor(m, off, 64));
    const float ex = __expf(e - m);
    float sum = ex;
#pragma unroll
    for (int off = 16; off > 0; off >>= 1) sum += __shfl_xor(sum, off, 64);
    wts[bs] = ex / sum;
}

// Kernel D: context[b,c,p] = sum_s w[b,s]*enc[b,s,c,p]  (float4 coalesced)
__global__ __launch_bounds__(256) void context_kernel(const float4* __restrict__ enc4,
                                                      const float* __restrict__ wts,
                                                      float4* __restrict__ out4) {
    const int bi = blockIdx.x;                       // 1024
    const int b  = bi >> 6;
    const int i4 = ((bi & 63) << 8) + threadIdx.x;   // [0,16384) float4s over C*P
    float4 acc = {0.f, 0.f, 0.f, 0.f};
    const float4* eb = enc4 + (size_t)b * SDIM * 16384 + i4;
#pragma unroll 4
    for (int s = 0; s < SDIM; ++s) {
        const float wv = wts[b * SDIM + s];          // uniform -> scalar load
        const float4 v = eb[(size_t)s * 16384];
        acc.x = fmaf(wv, v.x, acc.x);
        acc.y = fmaf(wv, v.y, acc.y);
        acc.z = fmaf(wv, v.z, acc.z);
        acc.w = fmaf(wv, v.w, acc.w);
    }
    out4[(size_t)b * 16384 + i4] = acc;
}

extern "C" void kernel_launch(void* const* d_in, const int* in_sizes, int n_in,
                              void* d_out, int out_size, void* d_ws, size_t ws_size,
                              hipStream_t stream) {
    const float* hid = (const float*)d_in[0];
    const float* enc = (const float*)d_in[1];
    const float* W1  = (const float*)d_in[2];
    const float* b1  = (const float*)d_in[3];
    const float* W2  = (const float*)d_in[4];
    const float* b2  = (const float*)d_in[5];
    float* out = (float*)d_out;

    float* ehb1    = out;               // d_out reused as 4MB scratch; fully overwritten by context
    float* partial = (float*)d_ws;      // 1024 floats
    float* wts     = partial + 1024;    // 512 floats

    eh_kernel<<<256, 256, 0, stream>>>(hid, W1, b1, ehb1);
    energy_mfma<<<1024, 512, 0, stream>>>(enc, W1, W2, ehb1, partial);
    softmax_kernel<<<1, 512, 0, stream>>>(partial, b2, wts);
    context_kernel<<<1024, 256, 0, stream>>>((const float4*)enc, wts, (float4*)out);
}

// Round 4
// 125.527 us; speedup vs baseline: 118.2100x; 1.1498x over previous
//
#include <hip/hip_runtime.h>

#define P 256     // H*W
#define CDIM 256
#define SDIM 32

typedef __attribute__((ext_vector_type(8))) short short8;   // 8 bf16 = 4 VGPR
typedef __attribute__((ext_vector_type(4))) float f32x4;
typedef __attribute__((ext_vector_type(4))) unsigned int uint4v;

__device__ inline unsigned int pack2bf(float lo, float hi) {
    unsigned int ul = __builtin_bit_cast(unsigned int, lo);
    unsigned int uh = __builtin_bit_cast(unsigned int, hi);
    ul += 0x7fffu + ((ul >> 16) & 1u);   // RNE
    uh += 0x7fffu + ((uh >> 16) & 1u);
    return (ul >> 16) | (uh & 0xffff0000u);
}

// Pack W1e (W1[:,256:]) to bf16 in MFMA-A-fragment-linear order:
// layout [m'=a>>4][kc=k>>3][i16=a&15][8 bf16]  -> af load = lane-linear 16B
__global__ __launch_bounds__(256) void pack_w1e(const float* __restrict__ W1,
                                                uint4v* __restrict__ packA) {
    const int t   = blockIdx.x * 256 + threadIdx.x;  // [0, 8192)
    const int a   = ((t >> 9) << 4) | (t & 15);
    const int kc  = (t >> 4) & 31;
    const float* src = W1 + (size_t)a * 512 + 256 + kc * 8;
    const float4 f0 = *(const float4*)src;
    const float4 f1 = *(const float4*)(src + 4);
    uint4v u;
    u.x = pack2bf(f0.x, f0.y);
    u.y = pack2bf(f0.z, f0.w);
    u.z = pack2bf(f1.x, f1.y);
    u.w = pack2bf(f1.z, f1.w);
    packA[t] = u;
}

// Kernel A: ehb1[b,a,p] = sum_c W1h[a,c]*hid[b,c,p] + b1[a]   (fp32, exact)
__global__ __launch_bounds__(256) void eh_kernel(const float* __restrict__ hid,
                                                 const float* __restrict__ W1,
                                                 const float* __restrict__ b1,
                                                 float* __restrict__ ehb1) {
    const int bi = blockIdx.x;        // [0,256)
    const int b  = bi >> 4;
    const int ab = (bi & 15) << 4;
    const int p  = threadIdx.x;
    float acc[16];
#pragma unroll
    for (int i = 0; i < 16; ++i) acc[i] = 0.f;
    const float* hb = hid + (size_t)b * CDIM * P;
    for (int c = 0; c < CDIM; c += 8) {
        float hv[8];
#pragma unroll
        for (int j = 0; j < 8; ++j) hv[j] = hb[(c + j) * P + p];
#pragma unroll
        for (int i = 0; i < 16; ++i) {
            const float* wr = W1 + (size_t)(ab + i) * 512 + c;
#pragma unroll
            for (int j = 0; j < 8; ++j) acc[i] = fmaf(wr[j], hv[j], acc[i]);
        }
    }
#pragma unroll
    for (int i = 0; i < 16; ++i)
        ehb1[((size_t)b * CDIM + ab + i) * P + p] = acc[i] + b1[ab + i];
}

// Kernel B: bf16-MFMA energy. Block = 256 thr / 4 waves, tile 128a x 128p.
// bid scrambled so the (ah=0,ah=1) pair sharing an enc slice differ by 8
// (same XCD under round-robin dispatch -> L2 reuse).
// A fragments: direct global_load_dwordx4 from packA (L2-resident).
// B (enc^T bf16): double-buffered LDS, XOR-swizzled, 1 barrier per kt.
__global__ __launch_bounds__(256, 3) void energy_mfma(const float* __restrict__ enc,
                                                      const unsigned char* __restrict__ packA,
                                                      const float* __restrict__ W2,
                                                      const float* __restrict__ ehb1,
                                                      float* __restrict__ partial) {
    __shared__ __align__(16) unsigned char ldsB[2][128 * 128];  // [buf][128p][64c] bf16
    __shared__ float red[4];
    const int bid   = blockIdx.x;                   // 2048
    const int bs_ph = (bid & 7) | ((bid >> 4) << 3);
    const int ah    = (bid >> 3) & 1;
    const int bs    = bs_ph >> 1;
    const int ph    = bs_ph & 1;
    const int b     = bs >> 5;
    const int tid = threadIdx.x;
    const int l   = tid & 63;
    const int w   = tid >> 6;
    const int g   = l >> 4;
    const int i16 = l & 15;
    const int a_base = ah * 128 + (w >> 1) * 64;    // wave tile 64a x 64p
    const int p_base = (w & 1) * 64;
    const int p_l = tid & 127;                      // staging: pixel
    const int cg  = tid >> 7;                       // staging: c-half of the 64c tile
    const int swz = (p_l & 7) << 4;
    const float* eb = enc + (size_t)bs * (CDIM * P) + ph * 128;

    f32x4 acc[4][4];
#pragma unroll
    for (int m = 0; m < 4; ++m)
#pragma unroll
        for (int n = 0; n < 4; ++n) acc[m][n] = (f32x4){0.f, 0.f, 0.f, 0.f};

    // prologue: stage kt=0 into ldsB[0]
    {
        float v[32];
        const float* src = eb + (size_t)(cg * 32) * P + p_l;
#pragma unroll
        for (int j = 0; j < 32; ++j) v[j] = src[(size_t)j * P];
        unsigned char* dst = ldsB[0] + p_l * 128;
#pragma unroll
        for (int h = 0; h < 2; ++h) {
            const int c2 = cg * 64 + h * 32;
            uint4v ua, ub;
            ua.x = pack2bf(v[h*16+0],  v[h*16+1]);
            ua.y = pack2bf(v[h*16+2],  v[h*16+3]);
            ua.z = pack2bf(v[h*16+4],  v[h*16+5]);
            ua.w = pack2bf(v[h*16+6],  v[h*16+7]);
            ub.x = pack2bf(v[h*16+8],  v[h*16+9]);
            ub.y = pack2bf(v[h*16+10], v[h*16+11]);
            ub.z = pack2bf(v[h*16+12], v[h*16+13]);
            ub.w = pack2bf(v[h*16+14], v[h*16+15]);
            *(uint4v*)(dst + (c2 ^ swz))        = ua;
            *(uint4v*)(dst + ((c2 + 16) ^ swz)) = ub;
        }
    }
    __syncthreads();

#pragma unroll
    for (int kt = 0; kt < 4; ++kt) {
        // A fragments for this kt FIRST (L2 hits; MFMA waits only on these)
        short8 af[2][4];
#pragma unroll
        for (int kh = 0; kh < 2; ++kh)
#pragma unroll
            for (int m = 0; m < 4; ++m) {
                const int chunk = ((a_base >> 4) + m) * 32 + kt * 8 + kh * 4;
                af[kh][m] = __builtin_bit_cast(short8,
                    *(const uint4v*)(packA + (size_t)chunk * 256 + l * 16));
            }
        // issue next-kt enc loads (HBM latency hides under MFMA below)
        float v[32];
        if (kt < 3) {
            const float* src = eb + (size_t)((kt + 1) * 64 + cg * 32) * P + p_l;
#pragma unroll
            for (int j = 0; j < 32; ++j) v[j] = src[(size_t)j * P];
        }
        // MFMA on current buffer
#pragma unroll
        for (int kh = 0; kh < 2; ++kh) {
            short8 bf[4];
#pragma unroll
            for (int n = 0; n < 4; ++n) {
                const int row = p_base + n * 16 + i16;
                bf[n] = __builtin_bit_cast(short8,
                    *(const uint4v*)(ldsB[kt & 1] + row * 128 +
                                     (((kh * 4 + g) * 16) ^ ((row & 7) << 4))));
            }
#pragma unroll
            for (int m = 0; m < 4; ++m)
#pragma unroll
                for (int n = 0; n < 4; ++n)
                    acc[m][n] = __builtin_amdgcn_mfma_f32_16x16x32_bf16(af[kh][m], bf[n], acc[m][n], 0, 0, 0);
        }
        // write-late: pack + ds_write next buffer, one barrier
        if (kt < 3) {
            unsigned char* dst = ldsB[(kt + 1) & 1] + p_l * 128;
#pragma unroll
            for (int h = 0; h < 2; ++h) {
                const int c2 = cg * 64 + h * 32;
                uint4v ua, ub;
                ua.x = pack2bf(v[h*16+0],  v[h*16+1]);
                ua.y = pack2bf(v[h*16+2],  v[h*16+3]);
                ua.z = pack2bf(v[h*16+4],  v[h*16+5]);
                ua.w = pack2bf(v[h*16+6],  v[h*16+7]);
                ub.x = pack2bf(v[h*16+8],  v[h*16+9]);
                ub.y = pack2bf(v[h*16+10], v[h*16+11]);
                ub.z = pack2bf(v[h*16+12], v[h*16+13]);
                ub.w = pack2bf(v[h*16+14], v[h*16+15]);
                *(uint4v*)(dst + (c2 ^ swz))        = ua;
                *(uint4v*)(dst + ((c2 + 16) ^ swz)) = ub;
            }
            __syncthreads();
        }
    }

    // epilogue: x = acc + ehb1; tanh; dot W2; block-reduce
    float ep = 0.f;
    const float* ehbB = ehb1 + (size_t)b * (CDIM * P);
    const int p_glob = ph * 128 + p_base + i16;
#pragma unroll
    for (int m = 0; m < 4; ++m) {
#pragma unroll
        for (int r = 0; r < 4; ++r) {
            const int a = a_base + m * 16 + g * 4 + r;   // C/D: row=(lane>>4)*4+reg
            const float w2v = W2[a];
            const float* ehr = ehbB + (size_t)a * P + p_glob;
#pragma unroll
            for (int n = 0; n < 4; ++n) {
                const float x  = acc[m][n][r] + ehr[n * 16];
                const float ex = __expf(2.f * x);
                const float t  = 1.f - 2.f / (ex + 1.f);
                ep = fmaf(w2v, t, ep);
            }
        }
    }
#pragma unroll
    for (int off = 32; off > 0; off >>= 1) ep += __shfl_down(ep, off, 64);
    if (l == 0) red[w] = ep;
    __syncthreads();
    if (tid == 0)
        partial[(size_t)bs * 4 + ph * 2 + ah] = red[0] + red[1] + red[2] + red[3];
}

// Kernel C: combine 4 partials per (b,s) + softmax over S=32 per batch
__global__ __launch_bounds__(512) void softmax_kernel(const float* __restrict__ partial,
                                                      const float* __restrict__ b2,
                                                      float* __restrict__ wts) {
    const int tid = threadIdx.x;   // 512 = 16 rows x 32
    const int r = tid >> 5;
    const int s = tid & 31;
    const int bs = r * 32 + s;
    float e = (partial[bs * 4] + partial[bs * 4 + 1] + partial[bs * 4 + 2] + partial[bs * 4 + 3])
              * (1.f / 256.f) + b2[0];
    float m = e;
#pragma unroll
    for (int off = 16; off > 0; off >>= 1) m = fmaxf(m, __shfl_xor(m, off, 64));
    const float ex = __expf(e - m);
    float sum = ex;
#pragma unroll
    for (int off = 16; off > 0; off >>= 1) sum += __shfl_xor(sum, off, 64);
    wts[bs] = ex / sum;
}

// Kernel D: context[b,c,p] = sum_s w[b,s]*enc[b,s,c,p]  (float4 coalesced)
__global__ __launch_bounds__(256) void context_kernel(const float4* __restrict__ enc4,
                                                      const float* __restrict__ wts,
                                                      float4* __restrict__ out4) {
    const int bi = blockIdx.x;                       // 1024
    const int b  = bi >> 6;
    const int i4 = ((bi & 63) << 8) + threadIdx.x;   // [0,16384) float4s over C*P
    float4 acc = {0.f, 0.f, 0.f, 0.f};
    const float4* eb = enc4 + (size_t)b * SDIM * 16384 + i4;
#pragma unroll 4
    for (int s = 0; s < SDIM; ++s) {
        const float wv = wts[b * SDIM + s];          // uniform -> scalar load
        const float4 v = eb[(size_t)s * 16384];
        acc.x = fmaf(wv, v.x, acc.x);
        acc.y = fmaf(wv, v.y, acc.y);
        acc.z = fmaf(wv, v.z, acc.z);
        acc.w = fmaf(wv, v.w, acc.w);
    }
    out4[(size_t)b * 16384 + i4] = acc;
}

extern "C" void kernel_launch(void* const* d_in, const int* in_sizes, int n_in,
                              void* d_out, int out_size, void* d_ws, size_t ws_size,
                              hipStream_t stream) {
    const float* hid = (const float*)d_in[0];
    const float* enc = (const float*)d_in[1];
    const float* W1  = (const float*)d_in[2];
    const float* b1  = (const float*)d_in[3];
    const float* W2  = (const float*)d_in[4];
    const float* b2  = (const float*)d_in[5];
    float* out = (float*)d_out;

    float* ehb1    = out;                       // d_out reused as 4MB scratch
    float* partial = (float*)d_ws;              // 2048 floats
    float* wts     = partial + 2048;            // 512 floats
    unsigned char* packA = (unsigned char*)(wts + 512);   // 128KB bf16 W1e (16B-aligned offset)

    pack_w1e<<<32, 256, 0, stream>>>(W1, (uint4v*)packA);
    eh_kernel<<<256, 256, 0, stream>>>(hid, W1, b1, ehb1);
    energy_mfma<<<2048, 256, 0, stream>>>(enc, packA, W2, ehb1, partial);
    softmax_kernel<<<1, 512, 0, stream>>>(partial, b2, wts);
    context_kernel<<<1024, 256, 0, stream>>>((const float4*)enc, wts, (float4*)out);
}